// Round 1
// baseline (584.050 us; speedup 1.0000x reference)
//
#include <hip/hip_runtime.h>
#include <hip/hip_bf16.h>
#include <math.h>

#define BB 8
#define TT 2048
#define CC 1024
#define HH 64
#define BT (BB * TT)   // 16384 rows

// ---------------------------------------------------------------------------
// Kernel 1: QKV projection.  out[m] = x[16384x1024] @ W[1024x64] for m in {q,k,v}
// grid = (BT/64, 3), block = 256.  Each block: 64x64 output tile, K-chunks of 16.
// LDS: xs stored transposed [kk][row] with stride 68 (16B-aligned rows, 2-way
// bank aliasing only = free).  Each thread computes a 4x4 register tile.
// ---------------------------------------------------------------------------
__global__ __launch_bounds__(256) void qkv_kernel(
    const float* __restrict__ x, const float* __restrict__ Wq,
    const float* __restrict__ Wk, const float* __restrict__ Wv,
    float* __restrict__ qo, float* __restrict__ ko, float* __restrict__ vo)
{
    __shared__ float xs[16][68];   // [kk][row], padded stride 68
    __shared__ float Wt[16][64];   // [kk][col]

    const float* W  = (blockIdx.y == 0) ? Wq : (blockIdx.y == 1) ? Wk : Wv;
    float*      out = (blockIdx.y == 0) ? qo : (blockIdx.y == 1) ? ko : vo;

    const int row0 = blockIdx.x * 64;
    const int t  = threadIdx.x;
    const int ty = t >> 4;          // 0..15 -> rows ty*4..ty*4+3
    const int tx = t & 15;          // 0..15 -> cols tx*4..tx*4+3

    float acc[4][4] = {};

    for (int c0 = 0; c0 < CC; c0 += 16) {
        // ---- stage x tile (64 rows x 16 k) transposed into LDS ----
        {
            const int lr = t >> 2;              // 0..63 row
            const int lc = (t & 3) << 2;        // 0,4,8,12
            float4 xv = *(const float4*)&x[(size_t)(row0 + lr) * CC + c0 + lc];
            xs[lc + 0][lr] = xv.x;
            xs[lc + 1][lr] = xv.y;
            xs[lc + 2][lr] = xv.z;
            xs[lc + 3][lr] = xv.w;
        }
        // ---- stage W tile (16 k x 64 cols) ----
        {
            const int wk = t >> 4;              // 0..15
            const int wc = (t & 15) << 2;       // 0..60
            *(float4*)&Wt[wk][wc] = *(const float4*)&W[(size_t)(c0 + wk) * HH + wc];
        }
        __syncthreads();

        #pragma unroll
        for (int kk = 0; kk < 16; ++kk) {
            float4 a = *(const float4*)&xs[kk][ty << 2];
            float4 b = *(const float4*)&Wt[kk][tx << 2];
            acc[0][0] += a.x * b.x; acc[0][1] += a.x * b.y; acc[0][2] += a.x * b.z; acc[0][3] += a.x * b.w;
            acc[1][0] += a.y * b.x; acc[1][1] += a.y * b.y; acc[1][2] += a.y * b.z; acc[1][3] += a.y * b.w;
            acc[2][0] += a.z * b.x; acc[2][1] += a.z * b.y; acc[2][2] += a.z * b.z; acc[2][3] += a.z * b.w;
            acc[3][0] += a.w * b.x; acc[3][1] += a.w * b.y; acc[3][2] += a.w * b.z; acc[3][3] += a.w * b.w;
        }
        __syncthreads();
    }

    #pragma unroll
    for (int i = 0; i < 4; ++i) {
        float4 o = make_float4(acc[i][0], acc[i][1], acc[i][2], acc[i][3]);
        *(float4*)&out[(size_t)(row0 + (ty << 2) + i) * HH + (tx << 2)] = o;
    }
}

// ---------------------------------------------------------------------------
// Kernel 2: flash attention (causal), fp32.
// grid = (T/64, B), block = 256 (4 waves).  Block handles 64 query rows of
// one batch.  Thread t: row r = t&63, dim-group g = t>>6 (dims g*16..g*16+15).
// q row held in 64 VGPRs; K/V tiles (64x64) staged in LDS; online softmax.
// ---------------------------------------------------------------------------
__global__ __launch_bounds__(256) void attn_kernel(
    const float* __restrict__ q, const float* __restrict__ k,
    const float* __restrict__ v, float* __restrict__ out)
{
    __shared__ float ks[64][64];       // key tile   (b128 reads are wave-broadcast)
    __shared__ float vs[64][64];       // value tile
    __shared__ float S [64][65];       // P tile, padded (2-way = free)
    __shared__ float pmax[4][64];
    __shared__ float psum[4][64];
    __shared__ float m_s[64];
    __shared__ float l_s[64];

    const int b  = blockIdx.y;
    const int qs = blockIdx.x * 64;
    const int t  = threadIdx.x;
    const int r  = t & 63;
    const int g  = t >> 6;
    const size_t base = (size_t)b * TT * HH;

    // load my q row into registers (16 x float4)
    float qreg[64];
    {
        const float4* qr = (const float4*)&q[base + (size_t)(qs + r) * HH];
        #pragma unroll
        for (int d4 = 0; d4 < 16; ++d4) {
            float4 x4 = qr[d4];
            qreg[4*d4+0] = x4.x; qreg[4*d4+1] = x4.y;
            qreg[4*d4+2] = x4.z; qreg[4*d4+3] = x4.w;
        }
    }
    if (t < 64) { m_s[t] = -1e30f; l_s[t] = 0.0f; }

    float o_acc[16] = {};

    const int ntiles = (qs >> 6) + 1;
    for (int kt = 0; kt < ntiles; ++kt) {
        const int ks0 = kt * 64;
        __syncthreads();   // protect ks/vs/S/pmax/psum from previous iteration readers

        // ---- cooperative load of K and V tiles (16 KB each), fully coalesced ----
        #pragma unroll
        for (int i = 0; i < 4; ++i) {
            const int idx = t + i * 256;        // float4 index 0..1023
            const int rr  = idx >> 4;           // 0..63
            const int cc  = (idx & 15) << 2;    // 0..60
            *(float4*)&ks[rr][cc] = *(const float4*)&k[base + (size_t)(ks0 + rr) * HH + cc];
            *(float4*)&vs[rr][cc] = *(const float4*)&v[base + (size_t)(ks0 + rr) * HH + cc];
        }
        __syncthreads();

        // ---- scores for my 16 keys (kidx = g*16+kk) ----
        float s[16];
        float lm = -1e30f;
        #pragma unroll 4
        for (int kk = 0; kk < 16; ++kk) {
            const int kidx = (g << 4) + kk;
            const float4* kr = (const float4*)&ks[kidx][0];
            float acc = 0.0f;
            #pragma unroll
            for (int d4 = 0; d4 < 16; ++d4) {
                float4 kv = kr[d4];
                acc += qreg[4*d4+0]*kv.x + qreg[4*d4+1]*kv.y
                     + qreg[4*d4+2]*kv.z + qreg[4*d4+3]*kv.w;
            }
            acc *= 0.125f;                       // 1/sqrt(64)
            if (ks0 + kidx > qs + r) acc = -1e30f;   // causal mask
            s[kk] = acc;
            lm = fmaxf(lm, acc);
        }
        pmax[g][r] = lm;
        __syncthreads();

        // ---- online softmax: tile max, rescale, exponentiate ----
        const float tm    = fmaxf(fmaxf(pmax[0][r], pmax[1][r]),
                                  fmaxf(pmax[2][r], pmax[3][r]));
        const float m_old = m_s[r];
        const float m_new = fmaxf(m_old, tm);
        const float alpha = __expf(m_old - m_new);
        float lsum = 0.0f;
        #pragma unroll
        for (int kk = 0; kk < 16; ++kk) {
            const float p = __expf(s[kk] - m_new);
            S[r][(g << 4) + kk] = p;
            lsum += p;
        }
        psum[g][r] = lsum;
        __syncthreads();

        if (g == 0) {
            const float ts = psum[0][r] + psum[1][r] + psum[2][r] + psum[3][r];
            l_s[r] = l_s[r] * alpha + ts;
            m_s[r] = m_new;
        }

        // ---- PV accumulate: o[j] = o[j]*alpha + sum_k P[r][k] * V[k][g*16+j] ----
        #pragma unroll
        for (int j = 0; j < 16; ++j) o_acc[j] *= alpha;

        #pragma unroll 8
        for (int kk = 0; kk < 64; ++kk) {
            const float p = S[r][kk];
            const float4* vr = (const float4*)&vs[kk][g << 4];
            float4 v0 = vr[0], v1 = vr[1], v2 = vr[2], v3 = vr[3];
            o_acc[ 0] += p * v0.x; o_acc[ 1] += p * v0.y; o_acc[ 2] += p * v0.z; o_acc[ 3] += p * v0.w;
            o_acc[ 4] += p * v1.x; o_acc[ 5] += p * v1.y; o_acc[ 6] += p * v1.z; o_acc[ 7] += p * v1.w;
            o_acc[ 8] += p * v2.x; o_acc[ 9] += p * v2.y; o_acc[10] += p * v2.z; o_acc[11] += p * v2.w;
            o_acc[12] += p * v3.x; o_acc[13] += p * v3.y; o_acc[14] += p * v3.z; o_acc[15] += p * v3.w;
        }
    }
    __syncthreads();

    const float linv = 1.0f / l_s[r];
    float* orow = &out[base + (size_t)(qs + r) * HH + (g << 4)];
    *(float4*)&orow[ 0] = make_float4(o_acc[ 0]*linv, o_acc[ 1]*linv, o_acc[ 2]*linv, o_acc[ 3]*linv);
    *(float4*)&orow[ 4] = make_float4(o_acc[ 4]*linv, o_acc[ 5]*linv, o_acc[ 6]*linv, o_acc[ 7]*linv);
    *(float4*)&orow[ 8] = make_float4(o_acc[ 8]*linv, o_acc[ 9]*linv, o_acc[10]*linv, o_acc[11]*linv);
    *(float4*)&orow[12] = make_float4(o_acc[12]*linv, o_acc[13]*linv, o_acc[14]*linv, o_acc[15]*linv);
}

// ---------------------------------------------------------------------------
extern "C" void kernel_launch(void* const* d_in, const int* in_sizes, int n_in,
                              void* d_out, int out_size, void* d_ws, size_t ws_size,
                              hipStream_t stream)
{
    (void)in_sizes; (void)n_in; (void)out_size; (void)ws_size;
    const float* x  = (const float*)d_in[0];
    const float* Wq = (const float*)d_in[1];
    const float* Wk = (const float*)d_in[2];
    const float* Wv = (const float*)d_in[3];
    float* outp = (float*)d_out;

    // workspace: q, k, v  each BT*HH floats (4 MB) -> 12 MB total
    float* qb = (float*)d_ws;
    float* kb = qb + (size_t)BT * HH;
    float* vb = kb + (size_t)BT * HH;

    qkv_kernel<<<dim3(BT / 64, 3), 256, 0, stream>>>(x, Wq, Wk, Wv, qb, kb, vb);
    attn_kernel<<<dim3(TT / 64, BB), 256, 0, stream>>>(qb, kb, vb, outp);
}

// Round 2
// 362.946 us; speedup vs baseline: 1.6092x; 1.6092x over previous
//
#include <hip/hip_runtime.h>
#include <hip/hip_bf16.h>
#include <math.h>

#define BB 8
#define TT 2048
#define CC 1024
#define HH 64
#define BT (BB * TT)   // 16384 rows

typedef __attribute__((ext_vector_type(8))) short short8;   // bf16 x8 MFMA frag
typedef __attribute__((ext_vector_type(4))) float floatx4;  // MFMA acc

static __device__ inline ushort f2bf(float f) {
    __hip_bfloat16 h = __float2bfloat16(f);
    return *reinterpret_cast<ushort*>(&h);
}

// ---------------------------------------------------------------------------
// Kernel 1: QKV projection via bf16 MFMA, fp32 accumulate, fp32 outputs.
// grid = 256 blocks (64 rows each), block = 256 (4 waves, wave w = row-tile w).
// Output tile 64 x 192 (q|k|v).  K-loop BK=64 (2 chunks of 32 per mfma).
// LDS: As[2 planes][64 rows][32 k] bf16  (plane layout -> A-frag reads are
//      16 consecutive 64B rows = conflict-free);
//      Bt[2 planes][192 n][32 k] bf16   (B-operand layout, k-contiguous).
// ---------------------------------------------------------------------------
__global__ __launch_bounds__(256) void qkv_kernel(
    const float* __restrict__ x, const float* __restrict__ Wq,
    const float* __restrict__ Wk, const float* __restrict__ Wv,
    float* __restrict__ qo, float* __restrict__ ko, float* __restrict__ vo)
{
    __shared__ ushort As[2 * 64 * 32];    // 8 KB
    __shared__ ushort Bt[2 * 192 * 32];   // 24 KB

    const int row0 = blockIdx.x * 64;
    const int t    = threadIdx.x;
    const int w    = t >> 6;          // wave id = row-tile
    const int lane = t & 63;
    const int l16  = lane & 15;
    const int quad = lane >> 4;

    floatx4 acc[12];
    #pragma unroll
    for (int i = 0; i < 12; ++i) acc[i] = (floatx4){0.f, 0.f, 0.f, 0.f};

    // staging roles
    const int arow = t >> 2;          // 0..63
    const int aseg = t & 3;           // 0..3 (16 floats each)
    const int bn   = t & 63;          // 0..63 (W col)
    const int bkq  = t >> 6;          // 0..3

    for (int it = 0; it < 16; ++it) {
        const int k0 = it * 64;
        __syncthreads();  // protect LDS from previous iteration's readers

        // ---- stage A: x[row0..row0+63][k0..k0+63] -> bf16, 2 planes of 32 ----
        {
            const float4* src = (const float4*)&x[(size_t)(row0 + arow) * CC + k0 + aseg * 16];
            float4 a0 = src[0], a1 = src[1], a2 = src[2], a3 = src[3];
            union { ushort s[16]; uint4 q[2]; } u;
            u.s[ 0]=f2bf(a0.x); u.s[ 1]=f2bf(a0.y); u.s[ 2]=f2bf(a0.z); u.s[ 3]=f2bf(a0.w);
            u.s[ 4]=f2bf(a1.x); u.s[ 5]=f2bf(a1.y); u.s[ 6]=f2bf(a1.z); u.s[ 7]=f2bf(a1.w);
            u.s[ 8]=f2bf(a2.x); u.s[ 9]=f2bf(a2.y); u.s[10]=f2bf(a2.z); u.s[11]=f2bf(a2.w);
            u.s[12]=f2bf(a3.x); u.s[13]=f2bf(a3.y); u.s[14]=f2bf(a3.z); u.s[15]=f2bf(a3.w);
            const int plane = aseg >> 1;
            const int col   = (aseg & 1) * 16;
            uint4* dst = (uint4*)&As[plane * 2048 + arow * 32 + col];
            dst[0] = u.q[0];
            dst[1] = u.q[1];
        }
        // ---- stage B: W[k0..k0+63][0..63] x3 -> transposed bf16 Bt[n][k] ----
        #pragma unroll
        for (int m = 0; m < 3; ++m) {
            const float* Wm = (m == 0) ? Wq : (m == 1) ? Wk : Wv;
            #pragma unroll
            for (int kgi = 0; kgi < 2; ++kgi) {
                const int kg = bkq + kgi * 4;            // 0..7
                const int kb = k0 + kg * 8;
                union { ushort s[8]; uint4 q; } u;
                #pragma unroll
                for (int i = 0; i < 8; ++i)
                    u.s[i] = f2bf(Wm[(size_t)(kb + i) * HH + bn]);
                const int plane = kg >> 2;
                const int col   = (kg & 3) * 8;
                *(uint4*)&Bt[plane * (192 * 32) + (m * 64 + bn) * 32 + col] = u.q;
            }
        }
        __syncthreads();

        // ---- MFMA: 2 k-chunks x 12 col-tiles ----
        #pragma unroll
        for (int p = 0; p < 2; ++p) {
            short8 a = *(const short8*)&As[p * 2048 + (w * 16 + l16) * 32 + quad * 8];
            #pragma unroll
            for (int ct = 0; ct < 12; ++ct) {
                short8 b = *(const short8*)&Bt[p * (192 * 32) + (ct * 16 + l16) * 32 + quad * 8];
                acc[ct] = __builtin_amdgcn_mfma_f32_16x16x32_bf16(a, b, acc[ct], 0, 0, 0);
            }
        }
    }

    // ---- epilogue: C/D layout col=lane&15, row=quad*4+reg ----
    #pragma unroll
    for (int ct = 0; ct < 12; ++ct) {
        const int m  = ct >> 2;
        const int n0 = (ct & 3) * 16;
        float* outm = (m == 0) ? qo : (m == 1) ? ko : vo;
        const int rowb = row0 + w * 16 + quad * 4;
        const int col  = n0 + l16;
        #pragma unroll
        for (int reg = 0; reg < 4; ++reg)
            outm[(size_t)(rowb + reg) * HH + col] = acc[ct][reg];
    }
}

// ---------------------------------------------------------------------------
// Kernel 2: flash attention (causal), fp32 vector.
// grid = (64, 8) blocks, 256 threads.  Block handles 32 query rows (reversed
// order: heavy blocks launch first).  Thread: row r = t&31, dim-group
// g = t>>5 (dims g*8..g*8+7; keys g*8..g*8+7 in QK phase).
// ---------------------------------------------------------------------------
__global__ __launch_bounds__(256) void attn_kernel(
    const float* __restrict__ q, const float* __restrict__ k,
    const float* __restrict__ v, float* __restrict__ out)
{
    __shared__ float ks[64][64];       // 16 KB (reads are 2-way broadcast = free)
    __shared__ float vs[64][64];       // 16 KB
    __shared__ float S [32][68];       // padded, float4-aligned rows
    __shared__ float pmax[8][32];
    __shared__ float psum[8][32];
    __shared__ float m_s[32];
    __shared__ float l_s[32];

    const int b  = blockIdx.y;
    const int qi = gridDim.x - 1 - blockIdx.x;   // heavy-first launch order
    const int qs = qi * 32;
    const int t  = threadIdx.x;
    const int r  = t & 31;
    const int g  = t >> 5;                        // 0..7
    const size_t base = (size_t)b * TT * HH;

    // my q row (redundant across 8 g-threads; L2-hot)
    float qreg[64];
    {
        const float4* qr = (const float4*)&q[base + (size_t)(qs + r) * HH];
        #pragma unroll
        for (int d4 = 0; d4 < 16; ++d4) {
            float4 x4 = qr[d4];
            qreg[4*d4+0] = x4.x; qreg[4*d4+1] = x4.y;
            qreg[4*d4+2] = x4.z; qreg[4*d4+3] = x4.w;
        }
    }
    if (t < 32) { m_s[t] = -1e30f; l_s[t] = 0.0f; }

    float o_acc[8] = {};

    const int ntiles = (qs >> 6) + 1;
    for (int kt = 0; kt < ntiles; ++kt) {
        const int ks0 = kt * 64;
        __syncthreads();

        // ---- cooperative K/V tile load (16 KB each) ----
        #pragma unroll
        for (int i = 0; i < 4; ++i) {
            const int idx = t + i * 256;
            const int rr  = idx >> 4;
            const int cc  = (idx & 15) << 2;
            *(float4*)&ks[rr][cc] = *(const float4*)&k[base + (size_t)(ks0 + rr) * HH + cc];
            *(float4*)&vs[rr][cc] = *(const float4*)&v[base + (size_t)(ks0 + rr) * HH + cc];
        }
        __syncthreads();

        // ---- scores for my 8 keys ----
        float s[8];
        float lm = -1e30f;
        #pragma unroll
        for (int kk = 0; kk < 8; ++kk) {
            const int kidx = (g << 3) + kk;
            const float4* kr = (const float4*)&ks[kidx][0];
            float acc = 0.0f;
            #pragma unroll
            for (int d4 = 0; d4 < 16; ++d4) {
                float4 kv = kr[d4];
                acc += qreg[4*d4+0]*kv.x + qreg[4*d4+1]*kv.y
                     + qreg[4*d4+2]*kv.z + qreg[4*d4+3]*kv.w;
            }
            acc *= 0.125f;                         // 1/sqrt(64)
            if (ks0 + kidx > qs + r) acc = -1e30f; // causal
            s[kk] = acc;
            lm = fmaxf(lm, acc);
        }
        pmax[g][r] = lm;
        __syncthreads();

        // ---- online softmax ----
        float tm = pmax[0][r];
        #pragma unroll
        for (int gg = 1; gg < 8; ++gg) tm = fmaxf(tm, pmax[gg][r]);
        const float m_old = m_s[r];
        const float m_new = fmaxf(m_old, tm);
        const float alpha = __expf(m_old - m_new);
        float lsum = 0.0f;
        #pragma unroll
        for (int kk = 0; kk < 8; ++kk) {
            const float p = __expf(s[kk] - m_new);
            S[r][(g << 3) + kk] = p;
            lsum += p;
        }
        psum[g][r] = lsum;
        __syncthreads();

        if (t < 32) {
            float ts = psum[0][t];
            #pragma unroll
            for (int gg = 1; gg < 8; ++gg) ts += psum[gg][t];
            l_s[t] = l_s[t] * alpha + ts;
            m_s[t] = m_new;
        }

        // ---- PV accumulate over 64 keys, my 8 dims ----
        #pragma unroll
        for (int j = 0; j < 8; ++j) o_acc[j] *= alpha;

        #pragma unroll 4
        for (int c = 0; c < 16; ++c) {
            float4 p4 = *(const float4*)&S[r][c << 2];
            #pragma unroll
            for (int j = 0; j < 4; ++j) {
                const float p = (j == 0) ? p4.x : (j == 1) ? p4.y : (j == 2) ? p4.z : p4.w;
                const int kk = (c << 2) + j;
                const float4* vr = (const float4*)&vs[kk][g << 3];
                float4 v0 = vr[0], v1 = vr[1];
                o_acc[0] += p * v0.x; o_acc[1] += p * v0.y;
                o_acc[2] += p * v0.z; o_acc[3] += p * v0.w;
                o_acc[4] += p * v1.x; o_acc[5] += p * v1.y;
                o_acc[6] += p * v1.z; o_acc[7] += p * v1.w;
            }
        }
    }
    __syncthreads();

    const float linv = 1.0f / l_s[r];
    float* orow = &out[base + (size_t)(qs + r) * HH + (g << 3)];
    *(float4*)&orow[0] = make_float4(o_acc[0]*linv, o_acc[1]*linv, o_acc[2]*linv, o_acc[3]*linv);
    *(float4*)&orow[4] = make_float4(o_acc[4]*linv, o_acc[5]*linv, o_acc[6]*linv, o_acc[7]*linv);
}

// ---------------------------------------------------------------------------
extern "C" void kernel_launch(void* const* d_in, const int* in_sizes, int n_in,
                              void* d_out, int out_size, void* d_ws, size_t ws_size,
                              hipStream_t stream)
{
    (void)in_sizes; (void)n_in; (void)out_size; (void)ws_size;
    const float* x  = (const float*)d_in[0];
    const float* Wq = (const float*)d_in[1];
    const float* Wk = (const float*)d_in[2];
    const float* Wv = (const float*)d_in[3];
    float* outp = (float*)d_out;

    // workspace: q, k, v each BT*HH fp32 (4 MB) -> 12 MB
    float* qb = (float*)d_ws;
    float* kb = qb + (size_t)BT * HH;
    float* vb = kb + (size_t)BT * HH;

    qkv_kernel<<<dim3(BT / 64), 256, 0, stream>>>(x, Wq, Wk, Wv, qb, kb, vb);
    attn_kernel<<<dim3(TT / 32, BB), 256, 0, stream>>>(qb, kb, vb, outp);
}

// Round 4
// 200.124 us; speedup vs baseline: 2.9184x; 1.8136x over previous
//
#include <hip/hip_runtime.h>
#include <hip/hip_bf16.h>
#include <math.h>

#define BB 8
#define TT 2048
#define CC 1024
#define HH 64
#define BT (BB * TT)   // 16384 rows

typedef __attribute__((ext_vector_type(8))) short short8;   // bf16 x8 MFMA frag
typedef __attribute__((ext_vector_type(4))) float floatx4;  // MFMA acc

static __device__ inline ushort f2bf(float f) {
    __hip_bfloat16 h = __float2bfloat16(f);
    return *reinterpret_cast<ushort*>(&h);
}
static __device__ inline float bf2f(ushort u) {
    union { unsigned int i; float f; } c;
    c.i = ((unsigned int)u) << 16;
    return c.f;
}

// ---------------------------------------------------------------------------
// Kernel 0: W prep.  W[k][n] fp32 -> WbT[m][n][k] bf16 (B-operand layout,
// k-contiguous rows of 1024).  grid 48 x 256, one thread per (mn, k16-group).
// ---------------------------------------------------------------------------
__global__ __launch_bounds__(256) void wprep_kernel(
    const float* __restrict__ Wq, const float* __restrict__ Wk,
    const float* __restrict__ Wv, ushort* __restrict__ WbT)
{
    const int id  = blockIdx.x * 256 + threadIdx.x;  // 0..12287
    const int mn  = id >> 6;                         // 0..191
    const int k16 = id & 63;                         // 0..63
    const int m   = mn >> 6, n = mn & 63;
    const float* W = (m == 0) ? Wq : (m == 1) ? Wk : Wv;
    union { ushort s[16]; uint4 q[2]; } u;
    #pragma unroll
    for (int i = 0; i < 16; ++i)
        u.s[i] = f2bf(W[(size_t)(k16 * 16 + i) * HH + n]);
    *(uint4*)&WbT[(size_t)mn * 1024 + k16 * 16 + 0] = u.q[0];
    *(uint4*)&WbT[(size_t)mn * 1024 + k16 * 16 + 8] = u.q[1];
}

// ---------------------------------------------------------------------------
// Kernel 1: QKV via bf16 MFMA.  grid 256 (64-row tiles), block 256 (4 waves).
// Wave w owns col-tiles ct0=3w..3w+2 of the 192-wide (q|k|v) output and all
// 4 row-tiles.  Frag-major LDS: slot order == MFMA read order, so staging
// writes and frag reads are contiguous b128 (conflict-free).
// Outputs: qb,kb row-major bf16 [t][64]; v transposed vT[b][h][t] bf16.
// ---------------------------------------------------------------------------
__global__ __launch_bounds__(256) void qkv_kernel(
    const float* __restrict__ x, const ushort* __restrict__ WbT,
    ushort* __restrict__ qb, ushort* __restrict__ kb, ushort* __restrict__ vT)
{
    __shared__ ushort As[512 * 8];     // 8 KB : slot(p,mt,l16,q) = p*256+mt*64+l16*4+q
    __shared__ ushort Bt[1536 * 8];    // 24 KB: slot(p,ct,l16,q) = (p*12+ct)*64+l16*4+q

    const int row0 = blockIdx.x * 64;
    const int t    = threadIdx.x;
    const int w    = t >> 6;
    const int lane = t & 63;
    const int l16  = lane & 15;
    const int quad = lane >> 4;
    const int ct0  = w * 3;

    // --- precompute staging address components ---
    int arow[2], akoff[2];
    #pragma unroll
    for (int r = 0; r < 2; ++r) {
        const int c = r * 256 + t;
        const int p = c >> 8, wv = (c >> 6) & 3, ll = (c >> 2) & 15, q = c & 3;
        arow[r]  = wv * 16 + ll;
        akoff[r] = p * 32 + q * 8;
    }
    int boff[6];
    #pragma unroll
    for (int r = 0; r < 6; ++r) {
        const int c = r * 256 + t;
        const int p = c / 768, rem = c - p * 768;
        const int ct = rem >> 6, sub = rem & 63, ll = sub >> 2, q = sub & 3;
        boff[r] = (ct * 16 + ll) * 1024 + p * 32 + q * 8;   // + k0 per iter
    }

    floatx4 acc[4][3];
    #pragma unroll
    for (int mt = 0; mt < 4; ++mt)
        #pragma unroll
        for (int c = 0; c < 3; ++c) acc[mt][c] = (floatx4){0.f, 0.f, 0.f, 0.f};

    for (int it = 0; it < 16; ++it) {
        const int k0 = it * 64;
        __syncthreads();   // previous iteration's frag reads done

        // ---- stage A: fp32 x -> bf16, frag-major ----
        #pragma unroll
        for (int r = 0; r < 2; ++r) {
            const float4* src = (const float4*)&x[(size_t)(row0 + arow[r]) * CC + k0 + akoff[r]];
            float4 a0 = src[0], a1 = src[1];
            union { ushort s[8]; uint4 q; } u;
            u.s[0] = f2bf(a0.x); u.s[1] = f2bf(a0.y); u.s[2] = f2bf(a0.z); u.s[3] = f2bf(a0.w);
            u.s[4] = f2bf(a1.x); u.s[5] = f2bf(a1.y); u.s[6] = f2bf(a1.z); u.s[7] = f2bf(a1.w);
            *(uint4*)&As[(size_t)(r * 256 + t) * 8] = u.q;
        }
        // ---- stage B: already bf16 k-contiguous; straight 16B copies ----
        #pragma unroll
        for (int r = 0; r < 6; ++r) {
            uint4 d = *(const uint4*)&WbT[(size_t)boff[r] + k0];
            *(uint4*)&Bt[(size_t)(r * 256 + t) * 8] = d;
        }
        __syncthreads();

        // ---- MFMA: wave reads its 3 B-frags once per k-chunk, 4 row-tiles ----
        #pragma unroll
        for (int p = 0; p < 2; ++p) {
            short8 b[3];
            #pragma unroll
            for (int c = 0; c < 3; ++c)
                b[c] = *(const short8*)&Bt[(size_t)((p * 12 + ct0 + c) * 64 + l16 * 4 + quad) * 8];
            #pragma unroll
            for (int mt = 0; mt < 4; ++mt) {
                short8 a = *(const short8*)&As[(size_t)((p * 4 + mt) * 64 + l16 * 4 + quad) * 8];
                #pragma unroll
                for (int c = 0; c < 3; ++c)
                    acc[mt][c] = __builtin_amdgcn_mfma_f32_16x16x32_bf16(a, b[c], acc[mt][c], 0, 0, 0);
            }
        }
    }

    // ---- epilogue: C/D layout col=l16, row=quad*4+reg ----
    #pragma unroll
    for (int c = 0; c < 3; ++c) {
        const int ct    = ct0 + c;
        const int mtype = ct >> 2;
        const int n0    = (ct & 3) * 16;
        #pragma unroll
        for (int mt = 0; mt < 4; ++mt) {
            const int row = row0 + mt * 16 + quad * 4;
            if (mtype < 2) {
                ushort* dst = (mtype == 0) ? qb : kb;
                #pragma unroll
                for (int reg = 0; reg < 4; ++reg)
                    dst[(size_t)(row + reg) * HH + n0 + l16] = f2bf(acc[mt][c][reg]);
            } else {
                const int bb = row >> 11;       // batch (uniform per block)
                const int t0 = row & 2047;      // reg gives consecutive t
                union { ushort s[4]; uint2 q; } u;
                #pragma unroll
                for (int reg = 0; reg < 4; ++reg) u.s[reg] = f2bf(acc[mt][c][reg]);
                *(uint2*)&vT[(size_t)(bb * HH + n0 + l16) * TT + t0] = u.q;
            }
        }
    }
}

// ---------------------------------------------------------------------------
// Kernel 2: MFMA flash attention (causal).  grid 256 x 256 threads; each of
// the 1024 waves independently owns one (batch, 16-row q-tile), heavy-first.
// K/V B-frags straight from global (L2-hot); P round-trips through a
// per-wave LDS tile.  Row stride 72 ushorts (144 B): holds 64 cols, keeps
// ds_read_b128 16B-aligned, banks 2-way-only (free).
// ---------------------------------------------------------------------------
__global__ __launch_bounds__(256) void attn_kernel(
    const ushort* __restrict__ qb, const ushort* __restrict__ kb,
    const ushort* __restrict__ vT, float* __restrict__ out)
{
    __shared__ ushort P[4][16 * 72];   // per-wave 16x64 P tile, stride 72

    const int t    = threadIdx.x;
    const int w    = t >> 6;
    const int lane = t & 63;
    const int l16  = lane & 15;
    const int quad = lane >> 4;

    const int r  = blockIdx.x * 4 + w;            // 0..1023
    const int qi = (31 - (r >> 5)) * 4 + (r & 3); // heavy-first, 0..127
    const int b  = (r >> 2) & 7;
    const int ntiles = (qi >> 2) + 1;

    const size_t qkbase = (size_t)b * TT * HH;
    const ushort* kbase = kb + qkbase;
    const ushort* vbase = vT + (size_t)b * HH * TT;

    // Q A-frags (held for the whole wave)
    short8 qf[2];
    {
        const ushort* qrow = qb + qkbase + (size_t)(qi * 16) * HH;
        qf[0] = *(const short8*)&qrow[l16 * HH + quad * 8];
        qf[1] = *(const short8*)&qrow[l16 * HH + 32 + quad * 8];
    }

    floatx4 o[4];
    #pragma unroll
    for (int c = 0; c < 4; ++c) o[c] = (floatx4){0.f, 0.f, 0.f, 0.f};
    float mm[4] = {-1e30f, -1e30f, -1e30f, -1e30f};
    float ls[4] = {0.f, 0.f, 0.f, 0.f};

    ushort* Pw = &P[w][0];

    for (int kt = 0; kt < ntiles; ++kt) {
        const int ks0 = kt * 64;

        // ---- B-frag loads (issued up front; PV's vf overlap the softmax) ----
        short8 kf[4][2], vf[4][2];
        #pragma unroll
        for (int c = 0; c < 4; ++c) {
            #pragma unroll
            for (int p = 0; p < 2; ++p) {
                kf[c][p] = *(const short8*)&kbase[(size_t)(ks0 + c * 16 + l16) * HH + p * 32 + quad * 8];
                vf[c][p] = *(const short8*)&vbase[(size_t)(c * 16 + l16) * TT + ks0 + p * 32 + quad * 8];
            }
        }

        // ---- S = Q K^T ----
        floatx4 s[4];
        #pragma unroll
        for (int c = 0; c < 4; ++c) s[c] = (floatx4){0.f, 0.f, 0.f, 0.f};
        #pragma unroll
        for (int c = 0; c < 4; ++c)
            #pragma unroll
            for (int p = 0; p < 2; ++p)
                s[c] = __builtin_amdgcn_mfma_f32_16x16x32_bf16(qf[p], kf[c][p], s[c], 0, 0, 0);

        // ---- scale (+ causal mask on diagonal tile only) ----
        #pragma unroll
        for (int c = 0; c < 4; ++c)
            #pragma unroll
            for (int reg = 0; reg < 4; ++reg)
                s[c][reg] *= 0.125f;
        if (kt == ntiles - 1) {                    // wave-uniform branch
            const int qrow0 = qi * 16 + quad * 4;
            #pragma unroll
            for (int c = 0; c < 4; ++c)
                #pragma unroll
                for (int reg = 0; reg < 4; ++reg)
                    if (ks0 + c * 16 + l16 > qrow0 + reg) s[c][reg] = -1e30f;
        }

        // ---- online softmax (state per C-row = per reg) ----
        float tm[4];
        #pragma unroll
        for (int reg = 0; reg < 4; ++reg)
            tm[reg] = fmaxf(fmaxf(s[0][reg], s[1][reg]), fmaxf(s[2][reg], s[3][reg]));
        #pragma unroll
        for (int msk = 1; msk < 16; msk <<= 1)
            #pragma unroll
            for (int reg = 0; reg < 4; ++reg)
                tm[reg] = fmaxf(tm[reg], __shfl_xor(tm[reg], msk, 64));

        float al[4];
        #pragma unroll
        for (int reg = 0; reg < 4; ++reg) {
            const float mn = fmaxf(mm[reg], tm[reg]);
            al[reg] = __expf(mm[reg] - mn);
            mm[reg] = mn;
        }
        // exponentiate; accumulate the denominator from the bf16-ROUNDED P
        // (exactly what the PV MFMA will consume)
        float ps[4] = {0.f, 0.f, 0.f, 0.f};
        #pragma unroll
        for (int c = 0; c < 4; ++c)
            #pragma unroll
            for (int reg = 0; reg < 4; ++reg) {
                const ushort pu = f2bf(__expf(s[c][reg] - mm[reg]));
                Pw[(quad * 4 + reg) * 72 + c * 16 + l16] = pu;
                ps[reg] += bf2f(pu);
            }
        #pragma unroll
        for (int msk = 1; msk < 16; msk <<= 1)
            #pragma unroll
            for (int reg = 0; reg < 4; ++reg)
                ps[reg] += __shfl_xor(ps[reg], msk, 64);
        #pragma unroll
        for (int reg = 0; reg < 4; ++reg)
            ls[reg] = ls[reg] * al[reg] + ps[reg];

        // ---- rescale O ----
        #pragma unroll
        for (int c = 0; c < 4; ++c)
            #pragma unroll
            for (int reg = 0; reg < 4; ++reg)
                o[c][reg] *= al[reg];

        // ---- P (C-layout, now in LDS) -> A-layout frags ----
        short8 pf[2];
        pf[0] = *(const short8*)&Pw[l16 * 72 + quad * 8];
        pf[1] = *(const short8*)&Pw[l16 * 72 + 32 + quad * 8];

        // ---- O += P V  (B = vT, k-contiguous) ----
        #pragma unroll
        for (int c = 0; c < 4; ++c)
            #pragma unroll
            for (int p = 0; p < 2; ++p)
                o[c] = __builtin_amdgcn_mfma_f32_16x16x32_bf16(pf[p], vf[c][p], o[c], 0, 0, 0);
    }

    // ---- epilogue ----
    float linv[4];
    #pragma unroll
    for (int reg = 0; reg < 4; ++reg) linv[reg] = 1.0f / ls[reg];
    float* obase = out + (size_t)b * TT * HH + (size_t)(qi * 16) * HH;
    #pragma unroll
    for (int c = 0; c < 4; ++c)
        #pragma unroll
        for (int reg = 0; reg < 4; ++reg)
            obase[(size_t)(quad * 4 + reg) * HH + c * 16 + l16] = o[c][reg] * linv[reg];
}

// ---------------------------------------------------------------------------
extern "C" void kernel_launch(void* const* d_in, const int* in_sizes, int n_in,
                              void* d_out, int out_size, void* d_ws, size_t ws_size,
                              hipStream_t stream)
{
    (void)in_sizes; (void)n_in; (void)out_size; (void)ws_size;
    const float* x  = (const float*)d_in[0];
    const float* Wq = (const float*)d_in[1];
    const float* Wk = (const float*)d_in[2];
    const float* Wv = (const float*)d_in[3];
    float* outp = (float*)d_out;

    // ws layout: WbT (384 KB) | qb (2 MB) | kb (2 MB) | vT (2 MB)
    ushort* WbT = (ushort*)d_ws;
    ushort* qb  = (ushort*)((char*)d_ws + 393216);
    ushort* kb  = qb + (size_t)BT * HH;
    ushort* vTb = kb + (size_t)BT * HH;

    wprep_kernel<<<dim3(48),  256, 0, stream>>>(Wq, Wk, Wv, WbT);
    qkv_kernel <<<dim3(256), 256, 0, stream>>>(x, WbT, qb, kb, vTb);
    attn_kernel<<<dim3(256), 256, 0, stream>>>(qb, kb, vTb, outp);
}